// Round 8
// baseline (166.539 us; speedup 1.0000x reference)
//
#include <hip/hip_runtime.h>
#include <hip/hip_bf16.h>

#define B 8
#define N 25200
#define ROW 85
#define NC 80
#define K 2048
#define MAXDET 300
#define NBUCKET 16384
#define CAND_CAP 4096
#define NCHUNK 32   /* K/64 */
#define STILE 64    /* score tile rows */

// ---------------------------------------------------------------------------
// Kernel 1: score/cls per box + global 16384-bucket histogram (atomics spread
// over 131K counters -> negligible contention; hist zeroed by hipMemsetAsync).
// 64-row tile staged to LDS via coalesced float4 loads; 4 lanes per box;
// exact np.argmax first-max tie-break via shuffles.
// ---------------------------------------------------------------------------
__global__ void __launch_bounds__(256)
nms_score_kernel(const float* __restrict__ x,
                 float* __restrict__ scores,
                 int* __restrict__ cls_id,
                 unsigned* __restrict__ hist) {
    int b = blockIdx.y;
    int i0 = blockIdx.x * STILE;
    int rows = N - i0; if (rows > STILE) rows = STILE;
    __shared__ float lx[STILE * ROW];   // 21760 B
    {
        const float4* s4 = (const float4*)(x + ((size_t)b * N + i0) * ROW);
        float4* d4 = (float4*)lx;
        int nv = rows * ROW / 4;        // 1360 or 1020 (both exact)
        for (int k = threadIdx.x; k < nv; k += 256) d4[k] = s4[k];
    }
    __syncthreads();
    int g = threadIdx.x >> 2;          // box in tile
    int q = threadIdx.x & 3;
    if (g >= rows) return;             // uniform across the 4-lane group
    const float* p = lx + g * ROW;
    float obj = p[4];
    float best = -1e30f;
    int bc = 127;
    if (obj > 0.3f) {
        #pragma unroll
        for (int k = 0; k < 20; ++k) {
            int c = q + 4 * k;
            float v = __fmul_rn(p[5 + c], obj);   // exact, no FMA
            if (v > best) { best = v; bc = c; }   // strict >: in-lane first-max
        }
    }
    #pragma unroll
    for (int m = 1; m < 4; m <<= 1) {   // combine: higher v, tie -> smaller class
        float ov = __shfl_xor(best, m, 64);
        int   oc = __shfl_xor(bc, m, 64);
        if (ov > best || (ov == best && oc < bc)) { best = ov; bc = oc; }
    }
    if (q == 0) {
        int i = i0 + g;
        bool valid = (obj > 0.3f && best > 0.3f);
        scores[b * N + i] = valid ? best : -1.0f;
        cls_id[b * N + i] = (bc == 127) ? 0 : bc;
        if (valid) {
            int qq = (int)(__fmul_rn(best, 16384.0f));
            if (qq > NBUCKET - 1) qq = NBUCKET - 1;
            atomicAdd(&hist[b * NBUCKET + qq], 1u);
        }
    }
}

// ---------------------------------------------------------------------------
// Kernel 2 (fused select): coalesced hist->LDS load -> descending exclusive
// scan (uint4-vectorized LDS) -> single-pass counting-sort placement ->
// per-bucket insertion sort -> gather top-K boxes/cls/shifted/area.
// 128 KB LDS -> 1 block/CU.
// ---------------------------------------------------------------------------
__global__ void __launch_bounds__(1024, 1)
nms_select_kernel(const unsigned* __restrict__ hist,
                  const float* __restrict__ scores,
                  const float* __restrict__ x,
                  const int* __restrict__ cls_id,
                  float* __restrict__ top_s,
                  float* __restrict__ boxes,
                  int* __restrict__ clsk,
                  float* __restrict__ shifted,
                  float* __restrict__ area) {
    __shared__ unsigned loff[NBUCKET];          // hist staged, then start ranks
    __shared__ unsigned lcnt16[NBUCKET / 2];    // packed u16 cursors
    __shared__ unsigned long long lk[CAND_CAP]; // packed sort keys
    __shared__ unsigned wsum[16];

    int b = blockIdx.x;
    int t = threadIdx.x;
    int ln = t & 63, wv = t >> 6;

    {   // stage histogram (coalesced 64 KB), zero cursors + keys
        const uint4* src = (const uint4*)(hist + b * NBUCKET);
        uint4* d1 = (uint4*)loff;
        for (int k = t; k < NBUCKET / 4; k += 1024) d1[k] = src[k];
        uint4 z = {0u, 0u, 0u, 0u};
        uint4* d2 = (uint4*)lcnt16;
        for (int k = t; k < NBUCKET / 8; k += 1024) d2[k] = z;
    }
    for (int k = t; k < CAND_CAP; k += 1024) lk[k] = 0ULL;
    __syncthreads();

    // descending exclusive scan: loff[q] = count of elements in buckets > q.
    // thread t owns buckets NBUCKET-1-16t .. NBUCKET-16-16t; uint4 LDS ops.
    unsigned v[16];
    int base_j = t * 16;
    unsigned A4 = (unsigned)(NBUCKET - 16 - base_j) / 4;   // ascending uint4 base
    {
        uint4 u0 = ((uint4*)loff)[A4 + 0];
        uint4 u1 = ((uint4*)loff)[A4 + 1];
        uint4 u2 = ((uint4*)loff)[A4 + 2];
        uint4 u3 = ((uint4*)loff)[A4 + 3];
        unsigned u[16] = {u0.x,u0.y,u0.z,u0.w, u1.x,u1.y,u1.z,u1.w,
                          u2.x,u2.y,u2.z,u2.w, u3.x,u3.y,u3.z,u3.w};
        #pragma unroll
        for (int k = 0; k < 16; ++k) v[k] = u[15 - k];
    }
    unsigned S = 0;
    #pragma unroll
    for (int k = 0; k < 16; ++k) S += v[k];
    unsigned pref = S;
    #pragma unroll
    for (int o = 1; o < 64; o <<= 1) { unsigned u = __shfl_up(pref, o, 64); if (ln >= o) pref += u; }
    if (ln == 63) wsum[wv] = pref;
    __syncthreads();
    unsigned wbase = 0;
    for (int w = 0; w < wv; ++w) wbase += wsum[w];
    unsigned running = wbase + pref - S;
    {
        unsigned o[16];
        #pragma unroll
        for (int k = 0; k < 16; ++k) { o[15 - k] = running; running += v[k]; }
        ((uint4*)loff)[A4 + 0] = make_uint4(o[0],  o[1],  o[2],  o[3]);
        ((uint4*)loff)[A4 + 1] = make_uint4(o[4],  o[5],  o[6],  o[7]);
        ((uint4*)loff)[A4 + 2] = make_uint4(o[8],  o[9],  o[10], o[11]);
        ((uint4*)loff)[A4 + 3] = make_uint4(o[12], o[13], o[14], o[15]);
    }
    __syncthreads();

    // single-pass placement (counting sort)
    for (int i = t; i < N; i += 1024) {
        float s = scores[b * N + i];
        if (s > 0.0f) {
            int q = (int)(__fmul_rn(s, 16384.0f));
            if (q > NBUCKET - 1) q = NBUCKET - 1;
            unsigned start = loff[q];
            if (start < CAND_CAP) {
                unsigned sh = (q & 1) * 16;
                unsigned old = atomicAdd(&lcnt16[q >> 1], 1u << sh);
                unsigned rank = (old >> sh) & 0xFFFFu;
                unsigned pos = start + rank;
                if (pos < CAND_CAP) {
                    unsigned long long key =
                        ((unsigned long long)__float_as_uint(s) << 32) | (unsigned)(~i);
                    lk[pos] = key;
                }
            }
        }
    }
    __syncthreads();

    // per-bucket insertion sort (descending keys), disjoint ranges
    for (int q = t; q < NBUCKET; q += 1024) {
        unsigned start = loff[q];
        if (start < CAND_CAP) {
            unsigned c = (lcnt16[q >> 1] >> ((q & 1) * 16)) & 0xFFFFu;
            unsigned m = c;
            if (m > CAND_CAP - start) m = CAND_CAP - start;
            if (m >= 2) {
                for (unsigned a = start + 1; a < start + m; ++a) {
                    unsigned long long kv = lk[a];
                    unsigned p2 = a;
                    while (p2 > start && lk[p2 - 1] < kv) { lk[p2] = lk[p2 - 1]; --p2; }
                    lk[p2] = kv;
                }
            }
        }
    }
    __syncthreads();

    // gather top-K
    for (int r = t; r < K; r += 1024) {
        unsigned long long key = lk[r];
        float s;
        int idx;
        float x1, y1, x2, y2;
        int c;
        if (key == 0ULL) {
            s = -1.0f; x1 = y1 = x2 = y2 = 0.0f; c = 0;
        } else {
            s = __uint_as_float((unsigned)(key >> 32));
            idx = (int)(~(unsigned)key);
            const float* p = x + ((size_t)b * N + idx) * ROW;
            float cx = p[0], cy = p[1], w = p[2], h = p[3];
            float hx = __fmul_rn(w, 0.5f);
            float hy = __fmul_rn(h, 0.5f);
            x1 = __fsub_rn(cx, hx); y1 = __fsub_rn(cy, hy);
            x2 = __fadd_rn(cx, hx); y2 = __fadd_rn(cy, hy);
            c = cls_id[b * N + idx];
        }
        int o = b * K + r;
        top_s[o] = s;
        boxes[o * 4 + 0] = x1; boxes[o * 4 + 1] = y1;
        boxes[o * 4 + 2] = x2; boxes[o * 4 + 3] = y2;
        clsk[o] = c;
        float sh = __fmul_rn((float)c, 4096.0f);
        float sx1 = __fadd_rn(x1, sh), sy1 = __fadd_rn(y1, sh);
        float sx2 = __fadd_rn(x2, sh), sy2 = __fadd_rn(y2, sh);
        shifted[o * 4 + 0] = sx1; shifted[o * 4 + 1] = sy1;
        shifted[o * 4 + 2] = sx2; shifted[o * 4 + 3] = sy2;
        area[o] = __fmul_rn(__fsub_rn(sx2, sx1), __fsub_rn(sy2, sy1));
    }
}

// ---------------------------------------------------------------------------
// Kernel 3: transposed IoU bitmask, triangular grid packing. Also emits
// nzT[b][jb][ib] (bit t <=> row j0+t has any suppressor in chunk ib) so the
// reduce kernel's round 1 reads 8 KB instead of ~270 KB per batch.
// ---------------------------------------------------------------------------
__global__ void nms_mask_kernel(const float* __restrict__ shifted,
                                const float* __restrict__ area,
                                unsigned long long* __restrict__ maskT,
                                unsigned long long* __restrict__ nzT) {
    int L = blockIdx.x, b = blockIdx.y;
    int jb = (int)((__fsqrt_rn(8.0f * (float)L + 1.0f) - 1.0f) * 0.5f);
    while ((jb + 1) * (jb + 2) / 2 <= L) ++jb;   // fixup fp error
    while (jb * (jb + 1) / 2 > L) --jb;
    int ib = L - jb * (jb + 1) / 2;
    int t = threadIdx.x;   // 0..63
    int i = ib * 64 + t;

    __shared__ float jbox[64][4];
    __shared__ float jarea[64];
    int j0 = jb * 64;
    {
        const float* sb = shifted + ((size_t)b * K + j0 + t) * 4;
        jbox[t][0] = sb[0]; jbox[t][1] = sb[1]; jbox[t][2] = sb[2]; jbox[t][3] = sb[3];
        jarea[t] = area[b * K + j0 + t];
    }
    __syncthreads();

    const float* ab = shifted + ((size_t)b * K + i) * 4;
    float ax1 = ab[0], ay1 = ab[1], ax2 = ab[2], ay2 = ab[3];
    float aarea = area[b * K + i];

    unsigned long long mycol = 0ULL;
    for (int jl = 0; jl < 64; ++jl) {
        int j = j0 + jl;
        bool cond = false;
        if (j > i) {
            float lx = fmaxf(ax1, jbox[jl][0]);
            float ly = fmaxf(ay1, jbox[jl][1]);
            float rx = fminf(ax2, jbox[jl][2]);
            float ry = fminf(ay2, jbox[jl][3]);
            float w = fmaxf(__fsub_rn(rx, lx), 0.0f);
            float h = fmaxf(__fsub_rn(ry, ly), 0.0f);
            float inter = __fmul_rn(w, h);
            float denom = __fadd_rn(__fsub_rn(__fadd_rn(aarea, jarea[jl]), inter), 1e-9f);
            float iou = __fdiv_rn(inter, denom);   // exact ref order + division
            cond = iou > 0.6f;
        }
        unsigned long long colm = __ballot(cond);
        if (t == jl) mycol = colm;
    }
    maskT[((size_t)b * K + j0 + t) * NCHUNK + ib] = mycol;
    unsigned long long nzb = __ballot(mycol != 0ULL);
    if (t == 0) nzT[((size_t)b * NCHUNK + jb) * NCHUNK + ib] = nzb;
}

// ---------------------------------------------------------------------------
// Kernel 4: parallel fixpoint greedy reduce + fused top-300 output.
// Round 1 uses the nzT summary (coalesced 32 words per chunk, wave-OR);
// only the ~1% chained rows touch full maskT rows in later rounds.
// ---------------------------------------------------------------------------
__global__ void __launch_bounds__(1024)
nms_reduce_out_kernel(const unsigned long long* __restrict__ maskT,
                      const unsigned long long* __restrict__ nzT,
                      const float* __restrict__ top_s,
                      const float* __restrict__ boxes,
                      const int* __restrict__ clsk,
                      float* __restrict__ out) {
    int b = blockIdx.x;
    int t = threadIdx.x;
    int ln = t & 63, wv = t >> 6;   // 16 waves
    __shared__ unsigned long long kept[NCHUNK], decided[NCHUNK];
    __shared__ unsigned long long snapk[NCHUNK], snapd[NCHUNK];
    __shared__ int nundec;
    if (t == 0) nundec = 0;
    __syncthreads();

    int st[2];   // 1 = decided
    #pragma unroll
    for (int h = 0; h < 2; ++h) {
        int c = wv + h * 16;                 // chunk handled by this wave
        int j = c * 64 + ln;                 // == t + h*1024
        unsigned long long w = (ln < NCHUNK)
            ? nzT[((size_t)b * NCHUNK + c) * NCHUNK + ln] : 0ULL;
        #pragma unroll
        for (int m = 1; m < 64; m <<= 1) w |= __shfl_xor(w, m, 64);
        bool valid = top_s[b * K + j] > 0.0f;
        bool hassup = ((w >> ln) & 1ULL) != 0ULL;
        bool k_local = valid && !hassup;
        bool d_local = !valid || !hassup;
        st[h] = d_local ? 1 : 0;
        unsigned long long kb = __ballot(k_local);
        unsigned long long db = __ballot(d_local);
        if (ln == 0) {
            kept[c] = kb;
            decided[c] = db;
            if (~db != 0ULL) atomicAdd(&nundec, __popcll(~db));
        }
    }

    for (int round = 0; round < 2048; ++round) {
        __syncthreads();
        if (nundec == 0) break;
        if (t < NCHUNK) { snapd[t] = decided[t]; snapk[t] = kept[t]; }
        __syncthreads();
        #pragma unroll
        for (int h = 0; h < 2; ++h) {
            if (st[h]) continue;
            int j = t + h * 1024;
            const unsigned long long* row = maskT + ((size_t)b * K + j) * NCHUNK;
            int nw = (j >> 6) + 1;
            unsigned long long pend = 0ULL, sup = 0ULL;
            for (int w = 0; w < nw; ++w) {
                unsigned long long r = row[w];
                pend |= r & ~snapd[w];
                sup  |= r & snapk[w];
            }
            if (pend == 0ULL) {
                unsigned long long bit = 1ULL << (j & 63);
                if (sup == 0ULL) atomicOr(&kept[j >> 6], bit);
                atomicOr(&decided[j >> 6], bit);
                st[h] = 1;
                atomicSub(&nundec, 1);
            }
        }
    }
    __syncthreads();

    // fused output phase: wave 0 only (kept[] lives in LDS)
    if (wv == 0) {
        int lane = ln;
        int total = 0;
        for (int c = 0; c < NCHUNK; ++c) {
            bool k = ((kept[c] >> lane) & 1ULL) != 0ULL;
            unsigned long long m = __ballot(k);
            total += __popcll(m);
        }
        float* dets  = out + (size_t)b * MAXDET * 6;
        float* flags = out + (size_t)B * MAXDET * 6 + (size_t)b * MAXDET;
        unsigned long long below = (lane == 0) ? 0ULL : (~0ULL >> (64 - lane));
        int kc = 0, nc = 0;
        for (int c = 0; c < NCHUNK; ++c) {
            int i = c * 64 + lane;
            bool k = ((kept[c] >> lane) & 1ULL) != 0ULL;
            unsigned long long m = __ballot(k);
            int pc = __popcll(m);
            int slot = k ? (kc + __popcll(m & below))
                         : (total + nc + __popcll((~m) & below));
            if (slot < MAXDET) {
                int o = b * K + i;
                dets[slot * 6 + 0] = boxes[o * 4 + 0];
                dets[slot * 6 + 1] = boxes[o * 4 + 1];
                dets[slot * 6 + 2] = boxes[o * 4 + 2];
                dets[slot * 6 + 3] = boxes[o * 4 + 3];
                dets[slot * 6 + 4] = top_s[o];
                dets[slot * 6 + 5] = (float)clsk[o];
                flags[slot] = k ? 1.0f : 0.0f;
            }
            kc += pc;
            nc += 64 - pc;
        }
    }
}

// ---------------------------------------------------------------------------
extern "C" void kernel_launch(void* const* d_in, const int* in_sizes, int n_in,
                              void* d_out, int out_size, void* d_ws, size_t ws_size,
                              hipStream_t stream) {
    const float* x = (const float*)d_in[0];
    float* out = (float*)d_out;

    char* ws = (char*)d_ws;
    size_t off = 0;
    auto alloc = [&](size_t bytes) -> void* {
        void* p = ws + off;
        off += bytes;
        off = (off + 255) & ~(size_t)255;
        return p;
    };

    float*    scores = (float*)    alloc((size_t)B * N * 4);
    int*      cls_id = (int*)      alloc((size_t)B * N * 4);
    unsigned* hist   = (unsigned*) alloc((size_t)B * NBUCKET * 4);
    float*    top_s  = (float*)    alloc((size_t)B * K * 4);
    float*    boxes  = (float*)    alloc((size_t)B * K * 4 * 4);
    int*      clsk   = (int*)      alloc((size_t)B * K * 4);
    float*    shifted= (float*)    alloc((size_t)B * K * 4 * 4);
    float*    area   = (float*)    alloc((size_t)B * K * 4);
    unsigned long long* maskT = (unsigned long long*) alloc((size_t)B * K * NCHUNK * 8);
    unsigned long long* nzT   = (unsigned long long*) alloc((size_t)B * NCHUNK * NCHUNK * 8);
    (void)ws_size; // needs ~7.0 MB

    hipMemsetAsync(hist, 0, (size_t)B * NBUCKET * 4, stream);
    nms_score_kernel<<<dim3((N + STILE - 1) / STILE, B), 256, 0, stream>>>(x, scores, cls_id, hist);
    nms_select_kernel<<<B, 1024, 0, stream>>>(hist, scores, x, cls_id,
                                              top_s, boxes, clsk, shifted, area);
    nms_mask_kernel<<<dim3(NCHUNK * (NCHUNK + 1) / 2, B), 64, 0, stream>>>(shifted, area, maskT, nzT);
    nms_reduce_out_kernel<<<B, 1024, 0, stream>>>(maskT, nzT, top_s, boxes, clsk, out);
}

// Round 9
// 163.625 us; speedup vs baseline: 1.0178x; 1.0178x over previous
//
#include <hip/hip_runtime.h>
#include <hip/hip_bf16.h>

#define B 8
#define N 25200
#define ROW 85
#define NC 80
#define K 2048
#define MAXDET 300
#define NBUCKET 16384
#define CAND_CAP 4096
#define NCHUNK 32   /* K/64 */
#define STILE 64    /* score tile rows */

// Deterministic box recompute (bit-identical everywhere: fixed __f*_rn order).
__device__ __forceinline__ void box_xyxy(const float* __restrict__ x, int b, int idx,
                                         float& x1, float& y1, float& x2, float& y2) {
    const float* p = x + ((size_t)b * N + idx) * ROW;
    float cx = p[0], cy = p[1], w = p[2], h = p[3];
    float hx = __fmul_rn(w, 0.5f);
    float hy = __fmul_rn(h, 0.5f);
    x1 = __fsub_rn(cx, hx); y1 = __fsub_rn(cy, hy);
    x2 = __fadd_rn(cx, hx); y2 = __fadd_rn(cy, hy);
}

__device__ __forceinline__ void box_shifted(const float* __restrict__ x, int b, int idx, int cls,
                                            float& sx1, float& sy1, float& sx2, float& sy2, float& ar) {
    if (idx < 0) { sx1 = sy1 = sx2 = sy2 = 0.0f; ar = 0.0f; return; }
    float x1, y1, x2, y2;
    box_xyxy(x, b, idx, x1, y1, x2, y2);
    float sh = __fmul_rn((float)cls, 4096.0f);
    sx1 = __fadd_rn(x1, sh); sy1 = __fadd_rn(y1, sh);
    sx2 = __fadd_rn(x2, sh); sy2 = __fadd_rn(y2, sh);
    ar = __fmul_rn(__fsub_rn(sx2, sx1), __fsub_rn(sy2, sy1));
}

// ---------------------------------------------------------------------------
// Kernel 1: score/cls per box. 64-row tile staged to LDS via coalesced float4
// loads; 4 lanes per box; exact np.argmax first-max tie-break via shuffles.
// (R8 lesson: NO global histogram here — hist lives in select's LDS.)
// ---------------------------------------------------------------------------
__global__ void __launch_bounds__(256)
nms_score_kernel(const float* __restrict__ x,
                 float* __restrict__ scores,
                 int* __restrict__ cls_id) {
    int b = blockIdx.y;
    int i0 = blockIdx.x * STILE;
    int rows = N - i0; if (rows > STILE) rows = STILE;
    __shared__ float lx[STILE * ROW];   // 21760 B
    {
        const float4* s4 = (const float4*)(x + ((size_t)b * N + i0) * ROW);
        float4* d4 = (float4*)lx;
        int nv = rows * ROW / 4;        // 1360 or 1020 (both exact)
        for (int k = threadIdx.x; k < nv; k += 256) d4[k] = s4[k];
    }
    __syncthreads();
    int g = threadIdx.x >> 2;          // box in tile
    int q = threadIdx.x & 3;
    if (g >= rows) return;             // uniform across the 4-lane group
    const float* p = lx + g * ROW;
    float obj = p[4];
    float best = -1e30f;
    int bc = 127;
    if (obj > 0.3f) {
        #pragma unroll
        for (int k = 0; k < 20; ++k) {
            int c = q + 4 * k;
            float v = __fmul_rn(p[5 + c], obj);   // exact, no FMA
            if (v > best) { best = v; bc = c; }   // strict >: in-lane first-max
        }
    }
    #pragma unroll
    for (int m = 1; m < 4; m <<= 1) {   // combine: higher v, tie -> smaller class
        float ov = __shfl_xor(best, m, 64);
        int   oc = __shfl_xor(bc, m, 64);
        if (ov > best || (ov == best && oc < bc)) { best = ov; bc = oc; }
    }
    if (q == 0) {
        int i = i0 + g;
        float score = (obj > 0.3f && best > 0.3f) ? best : -1.0f;
        scores[b * N + i] = score;
        cls_id[b * N + i] = (bc == 127) ? 0 : bc;
    }
}

// ---------------------------------------------------------------------------
// Kernel 2 (fused select): LDS histogram (scores register-cached, single
// global pass) -> descending exclusive scan (uint4 LDS) -> counting-sort
// placement from registers -> per-bucket insertion sort -> emit ONLY
// top_s/top_i/clsk (24 KB coalesced; boxes recomputed downstream).
// 128 KB LDS -> 1 block/CU.
// ---------------------------------------------------------------------------
__global__ void __launch_bounds__(1024, 1)
nms_select_kernel(const float* __restrict__ scores,
                  const int* __restrict__ cls_id,
                  float* __restrict__ top_s,
                  int* __restrict__ top_i,
                  int* __restrict__ clsk) {
    __shared__ unsigned loff[NBUCKET];          // histogram, then start ranks
    __shared__ unsigned lcnt16[NBUCKET / 2];    // packed u16 cursors
    __shared__ unsigned long long lk[CAND_CAP]; // packed sort keys
    __shared__ unsigned wsum[16];

    int b = blockIdx.x;
    int t = threadIdx.x;
    int ln = t & 63, wv = t >> 6;
    constexpr int NITER = (N + 1023) / 1024;    // 25

    {   // zero histogram + cursors + keys
        uint4 z = {0u, 0u, 0u, 0u};
        uint4* d1 = (uint4*)loff;
        for (int k = t; k < NBUCKET / 4; k += 1024) d1[k] = z;
        uint4* d2 = (uint4*)lcnt16;
        for (int k = t; k < NBUCKET / 8; k += 1024) d2[k] = z;
    }
    for (int k = t; k < CAND_CAP; k += 1024) lk[k] = 0ULL;
    __syncthreads();

    // histogram pass: single global read, cache scores in registers
    float sreg[NITER];
    #pragma unroll
    for (int r = 0; r < NITER; ++r) {
        int i = t + r * 1024;
        float s = (i < N) ? scores[b * N + i] : -1.0f;
        sreg[r] = s;
        if (s > 0.0f) {
            int q = (int)(__fmul_rn(s, 16384.0f));
            if (q > NBUCKET - 1) q = NBUCKET - 1;
            atomicAdd(&loff[q], 1u);
        }
    }
    __syncthreads();

    // descending exclusive scan: loff[q] = count of elements in buckets > q
    unsigned v[16];
    int base_j = t * 16;
    unsigned A4 = (unsigned)(NBUCKET - 16 - base_j) / 4;   // ascending uint4 base
    {
        uint4 u0 = ((uint4*)loff)[A4 + 0];
        uint4 u1 = ((uint4*)loff)[A4 + 1];
        uint4 u2 = ((uint4*)loff)[A4 + 2];
        uint4 u3 = ((uint4*)loff)[A4 + 3];
        unsigned u[16] = {u0.x,u0.y,u0.z,u0.w, u1.x,u1.y,u1.z,u1.w,
                          u2.x,u2.y,u2.z,u2.w, u3.x,u3.y,u3.z,u3.w};
        #pragma unroll
        for (int k = 0; k < 16; ++k) v[k] = u[15 - k];
    }
    unsigned S = 0;
    #pragma unroll
    for (int k = 0; k < 16; ++k) S += v[k];
    unsigned pref = S;
    #pragma unroll
    for (int o = 1; o < 64; o <<= 1) { unsigned u = __shfl_up(pref, o, 64); if (ln >= o) pref += u; }
    if (ln == 63) wsum[wv] = pref;
    __syncthreads();
    unsigned wbase = 0;
    for (int w = 0; w < wv; ++w) wbase += wsum[w];
    unsigned running = wbase + pref - S;
    {
        unsigned o[16];
        #pragma unroll
        for (int k = 0; k < 16; ++k) { o[15 - k] = running; running += v[k]; }
        ((uint4*)loff)[A4 + 0] = make_uint4(o[0],  o[1],  o[2],  o[3]);
        ((uint4*)loff)[A4 + 1] = make_uint4(o[4],  o[5],  o[6],  o[7]);
        ((uint4*)loff)[A4 + 2] = make_uint4(o[8],  o[9],  o[10], o[11]);
        ((uint4*)loff)[A4 + 3] = make_uint4(o[12], o[13], o[14], o[15]);
    }
    __syncthreads();

    // placement (counting sort) from register-cached scores
    #pragma unroll
    for (int r = 0; r < NITER; ++r) {
        float s = sreg[r];
        if (s > 0.0f) {
            int i = t + r * 1024;
            int q = (int)(__fmul_rn(s, 16384.0f));
            if (q > NBUCKET - 1) q = NBUCKET - 1;
            unsigned start = loff[q];
            if (start < CAND_CAP) {
                unsigned sh = (q & 1) * 16;
                unsigned old = atomicAdd(&lcnt16[q >> 1], 1u << sh);
                unsigned rank = (old >> sh) & 0xFFFFu;
                unsigned pos = start + rank;
                if (pos < CAND_CAP) {
                    unsigned long long key =
                        ((unsigned long long)__float_as_uint(s) << 32) | (unsigned)(~i);
                    lk[pos] = key;
                }
            }
        }
    }
    __syncthreads();

    // per-bucket insertion sort (descending keys), disjoint ranges
    for (int q = t; q < NBUCKET; q += 1024) {
        unsigned start = loff[q];
        if (start < CAND_CAP) {
            unsigned c = (lcnt16[q >> 1] >> ((q & 1) * 16)) & 0xFFFFu;
            unsigned m = c;
            if (m > CAND_CAP - start) m = CAND_CAP - start;
            if (m >= 2) {
                for (unsigned a = start + 1; a < start + m; ++a) {
                    unsigned long long kv = lk[a];
                    unsigned p2 = a;
                    while (p2 > start && lk[p2 - 1] < kv) { lk[p2] = lk[p2 - 1]; --p2; }
                    lk[p2] = kv;
                }
            }
        }
    }
    __syncthreads();

    // emit top-K (s, idx, cls) — no box materialization
    for (int r = t; r < K; r += 1024) {
        unsigned long long key = lk[r];
        float s; int idx; int c;
        if (key == 0ULL) { s = -1.0f; idx = -1; c = 0; }
        else {
            s = __uint_as_float((unsigned)(key >> 32));
            idx = (int)(~(unsigned)key);
            c = cls_id[b * N + idx];
        }
        int o = b * K + r;
        top_s[o] = s;
        top_i[o] = idx;
        clsk[o] = c;
    }
}

// ---------------------------------------------------------------------------
// Kernel 3: transposed IoU bitmask, triangular grid packing; boxes recomputed
// from x (bit-identical). Emits nzT summary for the reduce kernel's round 1.
// ---------------------------------------------------------------------------
__global__ void nms_mask_kernel(const float* __restrict__ x,
                                const int* __restrict__ top_i,
                                const int* __restrict__ clsk,
                                unsigned long long* __restrict__ maskT,
                                unsigned long long* __restrict__ nzT) {
    int L = blockIdx.x, b = blockIdx.y;
    int jb = (int)((__fsqrt_rn(8.0f * (float)L + 1.0f) - 1.0f) * 0.5f);
    while ((jb + 1) * (jb + 2) / 2 <= L) ++jb;   // fixup fp error
    while (jb * (jb + 1) / 2 > L) --jb;
    int ib = L - jb * (jb + 1) / 2;
    int t = threadIdx.x;   // 0..63
    int i = ib * 64 + t;

    __shared__ float jbox[64][4];
    __shared__ float jarea[64];
    int j0 = jb * 64;
    {
        int jj = j0 + t;
        float sx1, sy1, sx2, sy2, ar;
        box_shifted(x, b, top_i[b * K + jj], clsk[b * K + jj], sx1, sy1, sx2, sy2, ar);
        jbox[t][0] = sx1; jbox[t][1] = sy1; jbox[t][2] = sx2; jbox[t][3] = sy2;
        jarea[t] = ar;
    }
    __syncthreads();

    float ax1, ay1, ax2, ay2, aarea;
    box_shifted(x, b, top_i[b * K + i], clsk[b * K + i], ax1, ay1, ax2, ay2, aarea);

    unsigned long long mycol = 0ULL;
    for (int jl = 0; jl < 64; ++jl) {
        int j = j0 + jl;
        bool cond = false;
        if (j > i) {
            float lx = fmaxf(ax1, jbox[jl][0]);
            float ly = fmaxf(ay1, jbox[jl][1]);
            float rx = fminf(ax2, jbox[jl][2]);
            float ry = fminf(ay2, jbox[jl][3]);
            float w = fmaxf(__fsub_rn(rx, lx), 0.0f);
            float h = fmaxf(__fsub_rn(ry, ly), 0.0f);
            float inter = __fmul_rn(w, h);
            float denom = __fadd_rn(__fsub_rn(__fadd_rn(aarea, jarea[jl]), inter), 1e-9f);
            float iou = __fdiv_rn(inter, denom);   // exact ref order + division
            cond = iou > 0.6f;
        }
        unsigned long long colm = __ballot(cond);
        if (t == jl) mycol = colm;
    }
    maskT[((size_t)b * K + j0 + t) * NCHUNK + ib] = mycol;
    unsigned long long nzb = __ballot(mycol != 0ULL);
    if (t == 0) nzT[((size_t)b * NCHUNK + jb) * NCHUNK + ib] = nzb;
}

// ---------------------------------------------------------------------------
// Kernel 4: parallel fixpoint greedy reduce + fused top-300 output.
// Round 1 uses the nzT summary; output boxes recomputed from x.
// ---------------------------------------------------------------------------
__global__ void __launch_bounds__(1024)
nms_reduce_out_kernel(const unsigned long long* __restrict__ maskT,
                      const unsigned long long* __restrict__ nzT,
                      const float* __restrict__ x,
                      const float* __restrict__ top_s,
                      const int* __restrict__ top_i,
                      const int* __restrict__ clsk,
                      float* __restrict__ out) {
    int b = blockIdx.x;
    int t = threadIdx.x;
    int ln = t & 63, wv = t >> 6;   // 16 waves
    __shared__ unsigned long long kept[NCHUNK], decided[NCHUNK];
    __shared__ unsigned long long snapk[NCHUNK], snapd[NCHUNK];
    __shared__ int nundec;
    if (t == 0) nundec = 0;
    __syncthreads();

    int st[2];   // 1 = decided
    #pragma unroll
    for (int h = 0; h < 2; ++h) {
        int c = wv + h * 16;                 // chunk handled by this wave
        int j = c * 64 + ln;                 // == t + h*1024
        unsigned long long w = (ln < NCHUNK)
            ? nzT[((size_t)b * NCHUNK + c) * NCHUNK + ln] : 0ULL;
        #pragma unroll
        for (int m = 1; m < 64; m <<= 1) w |= __shfl_xor(w, m, 64);
        bool valid = top_s[b * K + j] > 0.0f;
        bool hassup = ((w >> ln) & 1ULL) != 0ULL;
        bool k_local = valid && !hassup;
        bool d_local = !valid || !hassup;
        st[h] = d_local ? 1 : 0;
        unsigned long long kb = __ballot(k_local);
        unsigned long long db = __ballot(d_local);
        if (ln == 0) {
            kept[c] = kb;
            decided[c] = db;
            if (~db != 0ULL) atomicAdd(&nundec, __popcll(~db));
        }
    }

    for (int round = 0; round < 2048; ++round) {
        __syncthreads();
        if (nundec == 0) break;
        if (t < NCHUNK) { snapd[t] = decided[t]; snapk[t] = kept[t]; }
        __syncthreads();
        #pragma unroll
        for (int h = 0; h < 2; ++h) {
            if (st[h]) continue;
            int j = t + h * 1024;
            const unsigned long long* row = maskT + ((size_t)b * K + j) * NCHUNK;
            int nw = (j >> 6) + 1;
            unsigned long long pend = 0ULL, sup = 0ULL;
            for (int w = 0; w < nw; ++w) {
                unsigned long long r = row[w];
                pend |= r & ~snapd[w];
                sup  |= r & snapk[w];
            }
            if (pend == 0ULL) {
                unsigned long long bit = 1ULL << (j & 63);
                if (sup == 0ULL) atomicOr(&kept[j >> 6], bit);
                atomicOr(&decided[j >> 6], bit);
                st[h] = 1;
                atomicSub(&nundec, 1);
            }
        }
    }
    __syncthreads();

    // fused output phase: wave 0 only (kept[] lives in LDS)
    if (wv == 0) {
        int lane = ln;
        int total = 0;
        for (int c = 0; c < NCHUNK; ++c) {
            bool k = ((kept[c] >> lane) & 1ULL) != 0ULL;
            unsigned long long m = __ballot(k);
            total += __popcll(m);
        }
        float* dets  = out + (size_t)b * MAXDET * 6;
        float* flags = out + (size_t)B * MAXDET * 6 + (size_t)b * MAXDET;
        unsigned long long below = (lane == 0) ? 0ULL : (~0ULL >> (64 - lane));
        int kc = 0, nc = 0;
        for (int c = 0; c < NCHUNK; ++c) {
            int i = c * 64 + lane;
            bool k = ((kept[c] >> lane) & 1ULL) != 0ULL;
            unsigned long long m = __ballot(k);
            int pc = __popcll(m);
            int slot = k ? (kc + __popcll(m & below))
                         : (total + nc + __popcll((~m) & below));
            if (slot < MAXDET) {
                int o = b * K + i;
                int idx = top_i[o];
                float x1 = 0.0f, y1 = 0.0f, x2 = 0.0f, y2 = 0.0f;
                if (idx >= 0) box_xyxy(x, b, idx, x1, y1, x2, y2);
                dets[slot * 6 + 0] = x1;
                dets[slot * 6 + 1] = y1;
                dets[slot * 6 + 2] = x2;
                dets[slot * 6 + 3] = y2;
                dets[slot * 6 + 4] = top_s[o];
                dets[slot * 6 + 5] = (float)clsk[o];
                flags[slot] = k ? 1.0f : 0.0f;
            }
            kc += pc;
            nc += 64 - pc;
        }
    }
}

// ---------------------------------------------------------------------------
extern "C" void kernel_launch(void* const* d_in, const int* in_sizes, int n_in,
                              void* d_out, int out_size, void* d_ws, size_t ws_size,
                              hipStream_t stream) {
    const float* x = (const float*)d_in[0];
    float* out = (float*)d_out;

    char* ws = (char*)d_ws;
    size_t off = 0;
    auto alloc = [&](size_t bytes) -> void* {
        void* p = ws + off;
        off += bytes;
        off = (off + 255) & ~(size_t)255;
        return p;
    };

    float*    scores = (float*)    alloc((size_t)B * N * 4);
    int*      cls_id = (int*)      alloc((size_t)B * N * 4);
    float*    top_s  = (float*)    alloc((size_t)B * K * 4);
    int*      top_i  = (int*)      alloc((size_t)B * K * 4);
    int*      clsk   = (int*)      alloc((size_t)B * K * 4);
    unsigned long long* maskT = (unsigned long long*) alloc((size_t)B * K * NCHUNK * 8);
    unsigned long long* nzT   = (unsigned long long*) alloc((size_t)B * NCHUNK * NCHUNK * 8);
    (void)ws_size; // needs ~5.1 MB

    nms_score_kernel<<<dim3((N + STILE - 1) / STILE, B), 256, 0, stream>>>(x, scores, cls_id);
    nms_select_kernel<<<B, 1024, 0, stream>>>(scores, cls_id, top_s, top_i, clsk);
    nms_mask_kernel<<<dim3(NCHUNK * (NCHUNK + 1) / 2, B), 64, 0, stream>>>(x, top_i, clsk, maskT, nzT);
    nms_reduce_out_kernel<<<B, 1024, 0, stream>>>(maskT, nzT, x, top_s, top_i, clsk, out);
}

// Round 10
// 160.953 us; speedup vs baseline: 1.0347x; 1.0166x over previous
//
#include <hip/hip_runtime.h>
#include <hip/hip_bf16.h>

#define B 8
#define N 25200
#define ROW 85
#define NC 80
#define K 2048
#define MAXDET 300
#define NBUCKET 16384
#define CAND_CAP 4096
#define NCHUNK 32   /* K/64 */
#define STILE 64    /* score tile rows */

// ---------------------------------------------------------------------------
// Kernel 1: score/cls per box. 64-row tile staged to LDS via coalesced float4
// loads; 4 lanes per box; exact np.argmax first-max tie-break via shuffles.
// (R8 lesson: NO global histogram here — hist lives in select's LDS.)
// ---------------------------------------------------------------------------
__global__ void __launch_bounds__(256)
nms_score_kernel(const float* __restrict__ x,
                 float* __restrict__ scores,
                 int* __restrict__ cls_id) {
    int b = blockIdx.y;
    int i0 = blockIdx.x * STILE;
    int rows = N - i0; if (rows > STILE) rows = STILE;
    __shared__ float lx[STILE * ROW];   // 21760 B
    {
        const float4* s4 = (const float4*)(x + ((size_t)b * N + i0) * ROW);
        float4* d4 = (float4*)lx;
        int nv = rows * ROW / 4;        // 1360 or 1020 (both exact)
        for (int k = threadIdx.x; k < nv; k += 256) d4[k] = s4[k];
    }
    __syncthreads();
    int g = threadIdx.x >> 2;          // box in tile
    int q = threadIdx.x & 3;
    if (g >= rows) return;             // uniform across the 4-lane group
    const float* p = lx + g * ROW;
    float obj = p[4];
    float best = -1e30f;
    int bc = 127;
    if (obj > 0.3f) {
        #pragma unroll
        for (int k = 0; k < 20; ++k) {
            int c = q + 4 * k;
            float v = __fmul_rn(p[5 + c], obj);   // exact, no FMA
            if (v > best) { best = v; bc = c; }   // strict >: in-lane first-max
        }
    }
    #pragma unroll
    for (int m = 1; m < 4; m <<= 1) {   // combine: higher v, tie -> smaller class
        float ov = __shfl_xor(best, m, 64);
        int   oc = __shfl_xor(bc, m, 64);
        if (ov > best || (ov == best && oc < bc)) { best = ov; bc = oc; }
    }
    if (q == 0) {
        int i = i0 + g;
        float score = (obj > 0.3f && best > 0.3f) ? best : -1.0f;
        scores[b * N + i] = score;
        cls_id[b * N + i] = (bc == 127) ? 0 : bc;
    }
}

// ---------------------------------------------------------------------------
// Kernel 2 (fused select): LDS histogram (scores register-cached, single
// global pass) -> descending exclusive scan (uint4-vectorized LDS) ->
// counting-sort placement from registers -> per-bucket insertion sort ->
// gather top-K boxes/cls/shifted/area. 128 KB LDS -> 1 block/CU.
// ---------------------------------------------------------------------------
__global__ void __launch_bounds__(1024, 1)
nms_select_kernel(const float* __restrict__ scores,
                  const float* __restrict__ x,
                  const int* __restrict__ cls_id,
                  float* __restrict__ top_s,
                  float* __restrict__ boxes,
                  int* __restrict__ clsk,
                  float* __restrict__ shifted,
                  float* __restrict__ area) {
    __shared__ unsigned loff[NBUCKET];          // histogram, then start ranks
    __shared__ unsigned lcnt16[NBUCKET / 2];    // packed u16 cursors
    __shared__ unsigned long long lk[CAND_CAP]; // packed sort keys
    __shared__ unsigned wsum[16];

    int b = blockIdx.x;
    int t = threadIdx.x;
    int ln = t & 63, wv = t >> 6;
    constexpr int NITER = (N + 1023) / 1024;    // 25

    {   // zero histogram + cursors + keys
        uint4 z = {0u, 0u, 0u, 0u};
        uint4* d1 = (uint4*)loff;
        for (int k = t; k < NBUCKET / 4; k += 1024) d1[k] = z;
        uint4* d2 = (uint4*)lcnt16;
        for (int k = t; k < NBUCKET / 8; k += 1024) d2[k] = z;
    }
    for (int k = t; k < CAND_CAP; k += 1024) lk[k] = 0ULL;
    __syncthreads();

    // histogram pass: single global read, cache scores in registers
    float sreg[NITER];
    #pragma unroll
    for (int r = 0; r < NITER; ++r) {
        int i = t + r * 1024;
        float s = (i < N) ? scores[b * N + i] : -1.0f;
        sreg[r] = s;
        if (s > 0.0f) {
            int q = (int)(__fmul_rn(s, 16384.0f));
            if (q > NBUCKET - 1) q = NBUCKET - 1;
            atomicAdd(&loff[q], 1u);
        }
    }
    __syncthreads();

    // descending exclusive scan: loff[q] = count of elements in buckets > q.
    // thread t owns buckets NBUCKET-1-16t .. NBUCKET-16-16t; uint4 LDS ops.
    unsigned v[16];
    int base_j = t * 16;
    unsigned A4 = (unsigned)(NBUCKET - 16 - base_j) / 4;   // ascending uint4 base
    {
        uint4 u0 = ((uint4*)loff)[A4 + 0];
        uint4 u1 = ((uint4*)loff)[A4 + 1];
        uint4 u2 = ((uint4*)loff)[A4 + 2];
        uint4 u3 = ((uint4*)loff)[A4 + 3];
        unsigned u[16] = {u0.x,u0.y,u0.z,u0.w, u1.x,u1.y,u1.z,u1.w,
                          u2.x,u2.y,u2.z,u2.w, u3.x,u3.y,u3.z,u3.w};
        #pragma unroll
        for (int k = 0; k < 16; ++k) v[k] = u[15 - k];
    }
    unsigned S = 0;
    #pragma unroll
    for (int k = 0; k < 16; ++k) S += v[k];
    unsigned pref = S;
    #pragma unroll
    for (int o = 1; o < 64; o <<= 1) { unsigned u = __shfl_up(pref, o, 64); if (ln >= o) pref += u; }
    if (ln == 63) wsum[wv] = pref;
    __syncthreads();
    unsigned wbase = 0;
    for (int w = 0; w < wv; ++w) wbase += wsum[w];
    unsigned running = wbase + pref - S;
    {
        unsigned o[16];
        #pragma unroll
        for (int k = 0; k < 16; ++k) { o[15 - k] = running; running += v[k]; }
        ((uint4*)loff)[A4 + 0] = make_uint4(o[0],  o[1],  o[2],  o[3]);
        ((uint4*)loff)[A4 + 1] = make_uint4(o[4],  o[5],  o[6],  o[7]);
        ((uint4*)loff)[A4 + 2] = make_uint4(o[8],  o[9],  o[10], o[11]);
        ((uint4*)loff)[A4 + 3] = make_uint4(o[12], o[13], o[14], o[15]);
    }
    __syncthreads();

    // placement (counting sort) from register-cached scores
    #pragma unroll
    for (int r = 0; r < NITER; ++r) {
        float s = sreg[r];
        if (s > 0.0f) {
            int i = t + r * 1024;
            int q = (int)(__fmul_rn(s, 16384.0f));
            if (q > NBUCKET - 1) q = NBUCKET - 1;
            unsigned start = loff[q];
            if (start < CAND_CAP) {
                unsigned sh = (q & 1) * 16;
                unsigned old = atomicAdd(&lcnt16[q >> 1], 1u << sh);
                unsigned rank = (old >> sh) & 0xFFFFu;
                unsigned pos = start + rank;
                if (pos < CAND_CAP) {
                    unsigned long long key =
                        ((unsigned long long)__float_as_uint(s) << 32) | (unsigned)(~i);
                    lk[pos] = key;
                }
            }
        }
    }
    __syncthreads();

    // per-bucket insertion sort (descending keys), disjoint ranges
    for (int q = t; q < NBUCKET; q += 1024) {
        unsigned start = loff[q];
        if (start < CAND_CAP) {
            unsigned c = (lcnt16[q >> 1] >> ((q & 1) * 16)) & 0xFFFFu;
            unsigned m = c;
            if (m > CAND_CAP - start) m = CAND_CAP - start;
            if (m >= 2) {
                for (unsigned a = start + 1; a < start + m; ++a) {
                    unsigned long long kv = lk[a];
                    unsigned p2 = a;
                    while (p2 > start && lk[p2 - 1] < kv) { lk[p2] = lk[p2 - 1]; --p2; }
                    lk[p2] = kv;
                }
            }
        }
    }
    __syncthreads();

    // gather top-K
    for (int r = t; r < K; r += 1024) {
        unsigned long long key = lk[r];
        float s;
        int idx;
        float x1, y1, x2, y2;
        int c;
        if (key == 0ULL) {
            s = -1.0f; x1 = y1 = x2 = y2 = 0.0f; c = 0;
        } else {
            s = __uint_as_float((unsigned)(key >> 32));
            idx = (int)(~(unsigned)key);
            const float* p = x + ((size_t)b * N + idx) * ROW;
            float cx = p[0], cy = p[1], w = p[2], h = p[3];
            float hx = __fmul_rn(w, 0.5f);
            float hy = __fmul_rn(h, 0.5f);
            x1 = __fsub_rn(cx, hx); y1 = __fsub_rn(cy, hy);
            x2 = __fadd_rn(cx, hx); y2 = __fadd_rn(cy, hy);
            c = cls_id[b * N + idx];
        }
        int o = b * K + r;
        top_s[o] = s;
        boxes[o * 4 + 0] = x1; boxes[o * 4 + 1] = y1;
        boxes[o * 4 + 2] = x2; boxes[o * 4 + 3] = y2;
        clsk[o] = c;
        float sh = __fmul_rn((float)c, 4096.0f);
        float sx1 = __fadd_rn(x1, sh), sy1 = __fadd_rn(y1, sh);
        float sx2 = __fadd_rn(x2, sh), sy2 = __fadd_rn(y2, sh);
        shifted[o * 4 + 0] = sx1; shifted[o * 4 + 1] = sy1;
        shifted[o * 4 + 2] = sx2; shifted[o * 4 + 3] = sy2;
        area[o] = __fmul_rn(__fsub_rn(sx2, sx1), __fsub_rn(sy2, sy1));
    }
}

// ---------------------------------------------------------------------------
// Kernel 3: transposed IoU bitmask, triangular grid packing. Also emits
// nzT[b][jb][ib] (bit t <=> row j0+t has any suppressor in chunk ib) so the
// reduce kernel's round 1 reads 8 KB instead of ~270 KB per batch.
// ---------------------------------------------------------------------------
__global__ void nms_mask_kernel(const float* __restrict__ shifted,
                                const float* __restrict__ area,
                                unsigned long long* __restrict__ maskT,
                                unsigned long long* __restrict__ nzT) {
    int L = blockIdx.x, b = blockIdx.y;
    int jb = (int)((__fsqrt_rn(8.0f * (float)L + 1.0f) - 1.0f) * 0.5f);
    while ((jb + 1) * (jb + 2) / 2 <= L) ++jb;   // fixup fp error
    while (jb * (jb + 1) / 2 > L) --jb;
    int ib = L - jb * (jb + 1) / 2;
    int t = threadIdx.x;   // 0..63
    int i = ib * 64 + t;

    __shared__ float jbox[64][4];
    __shared__ float jarea[64];
    int j0 = jb * 64;
    {
        const float* sb = shifted + ((size_t)b * K + j0 + t) * 4;
        jbox[t][0] = sb[0]; jbox[t][1] = sb[1]; jbox[t][2] = sb[2]; jbox[t][3] = sb[3];
        jarea[t] = area[b * K + j0 + t];
    }
    __syncthreads();

    const float* ab = shifted + ((size_t)b * K + i) * 4;
    float ax1 = ab[0], ay1 = ab[1], ax2 = ab[2], ay2 = ab[3];
    float aarea = area[b * K + i];

    unsigned long long mycol = 0ULL;
    for (int jl = 0; jl < 64; ++jl) {
        int j = j0 + jl;
        bool cond = false;
        if (j > i) {
            float lx = fmaxf(ax1, jbox[jl][0]);
            float ly = fmaxf(ay1, jbox[jl][1]);
            float rx = fminf(ax2, jbox[jl][2]);
            float ry = fminf(ay2, jbox[jl][3]);
            float w = fmaxf(__fsub_rn(rx, lx), 0.0f);
            float h = fmaxf(__fsub_rn(ry, ly), 0.0f);
            float inter = __fmul_rn(w, h);
            float denom = __fadd_rn(__fsub_rn(__fadd_rn(aarea, jarea[jl]), inter), 1e-9f);
            float iou = __fdiv_rn(inter, denom);   // exact ref order + division
            cond = iou > 0.6f;
        }
        unsigned long long colm = __ballot(cond);
        if (t == jl) mycol = colm;
    }
    maskT[((size_t)b * K + j0 + t) * NCHUNK + ib] = mycol;
    unsigned long long nzb = __ballot(mycol != 0ULL);
    if (t == 0) nzT[((size_t)b * NCHUNK + jb) * NCHUNK + ib] = nzb;
}

// ---------------------------------------------------------------------------
// Kernel 4: parallel fixpoint greedy reduce + fused top-300 output.
// Round 1 uses the nzT summary (coalesced 32 words per chunk, wave-OR);
// only the ~1% chained rows touch full maskT rows in later rounds.
// ---------------------------------------------------------------------------
__global__ void __launch_bounds__(1024)
nms_reduce_out_kernel(const unsigned long long* __restrict__ maskT,
                      const unsigned long long* __restrict__ nzT,
                      const float* __restrict__ top_s,
                      const float* __restrict__ boxes,
                      const int* __restrict__ clsk,
                      float* __restrict__ out) {
    int b = blockIdx.x;
    int t = threadIdx.x;
    int ln = t & 63, wv = t >> 6;   // 16 waves
    __shared__ unsigned long long kept[NCHUNK], decided[NCHUNK];
    __shared__ unsigned long long snapk[NCHUNK], snapd[NCHUNK];
    __shared__ int nundec;
    if (t == 0) nundec = 0;
    __syncthreads();

    int st[2];   // 1 = decided
    #pragma unroll
    for (int h = 0; h < 2; ++h) {
        int c = wv + h * 16;                 // chunk handled by this wave
        int j = c * 64 + ln;                 // == t + h*1024
        unsigned long long w = (ln < NCHUNK)
            ? nzT[((size_t)b * NCHUNK + c) * NCHUNK + ln] : 0ULL;
        #pragma unroll
        for (int m = 1; m < 64; m <<= 1) w |= __shfl_xor(w, m, 64);
        bool valid = top_s[b * K + j] > 0.0f;
        bool hassup = ((w >> ln) & 1ULL) != 0ULL;
        bool k_local = valid && !hassup;
        bool d_local = !valid || !hassup;
        st[h] = d_local ? 1 : 0;
        unsigned long long kb = __ballot(k_local);
        unsigned long long db = __ballot(d_local);
        if (ln == 0) {
            kept[c] = kb;
            decided[c] = db;
            if (~db != 0ULL) atomicAdd(&nundec, __popcll(~db));
        }
    }

    for (int round = 0; round < 2048; ++round) {
        __syncthreads();
        if (nundec == 0) break;
        if (t < NCHUNK) { snapd[t] = decided[t]; snapk[t] = kept[t]; }
        __syncthreads();
        #pragma unroll
        for (int h = 0; h < 2; ++h) {
            if (st[h]) continue;
            int j = t + h * 1024;
            const unsigned long long* row = maskT + ((size_t)b * K + j) * NCHUNK;
            int nw = (j >> 6) + 1;
            unsigned long long pend = 0ULL, sup = 0ULL;
            for (int w = 0; w < nw; ++w) {
                unsigned long long r = row[w];
                pend |= r & ~snapd[w];
                sup  |= r & snapk[w];
            }
            if (pend == 0ULL) {
                unsigned long long bit = 1ULL << (j & 63);
                if (sup == 0ULL) atomicOr(&kept[j >> 6], bit);
                atomicOr(&decided[j >> 6], bit);
                st[h] = 1;
                atomicSub(&nundec, 1);
            }
        }
    }
    __syncthreads();

    // fused output phase: wave 0 only (kept[] lives in LDS)
    if (wv == 0) {
        int lane = ln;
        int total = 0;
        for (int c = 0; c < NCHUNK; ++c) {
            bool k = ((kept[c] >> lane) & 1ULL) != 0ULL;
            unsigned long long m = __ballot(k);
            total += __popcll(m);
        }
        float* dets  = out + (size_t)b * MAXDET * 6;
        float* flags = out + (size_t)B * MAXDET * 6 + (size_t)b * MAXDET;
        unsigned long long below = (lane == 0) ? 0ULL : (~0ULL >> (64 - lane));
        int kc = 0, nc = 0;
        for (int c = 0; c < NCHUNK; ++c) {
            int i = c * 64 + lane;
            bool k = ((kept[c] >> lane) & 1ULL) != 0ULL;
            unsigned long long m = __ballot(k);
            int pc = __popcll(m);
            int slot = k ? (kc + __popcll(m & below))
                         : (total + nc + __popcll((~m) & below));
            if (slot < MAXDET) {
                int o = b * K + i;
                dets[slot * 6 + 0] = boxes[o * 4 + 0];
                dets[slot * 6 + 1] = boxes[o * 4 + 1];
                dets[slot * 6 + 2] = boxes[o * 4 + 2];
                dets[slot * 6 + 3] = boxes[o * 4 + 3];
                dets[slot * 6 + 4] = top_s[o];
                dets[slot * 6 + 5] = (float)clsk[o];
                flags[slot] = k ? 1.0f : 0.0f;
            }
            kc += pc;
            nc += 64 - pc;
        }
    }
}

// ---------------------------------------------------------------------------
extern "C" void kernel_launch(void* const* d_in, const int* in_sizes, int n_in,
                              void* d_out, int out_size, void* d_ws, size_t ws_size,
                              hipStream_t stream) {
    const float* x = (const float*)d_in[0];
    float* out = (float*)d_out;

    char* ws = (char*)d_ws;
    size_t off = 0;
    auto alloc = [&](size_t bytes) -> void* {
        void* p = ws + off;
        off += bytes;
        off = (off + 255) & ~(size_t)255;
        return p;
    };

    float*    scores = (float*)    alloc((size_t)B * N * 4);
    int*      cls_id = (int*)      alloc((size_t)B * N * 4);
    float*    top_s  = (float*)    alloc((size_t)B * K * 4);
    float*    boxes  = (float*)    alloc((size_t)B * K * 4 * 4);
    int*      clsk   = (int*)      alloc((size_t)B * K * 4);
    float*    shifted= (float*)    alloc((size_t)B * K * 4 * 4);
    float*    area   = (float*)    alloc((size_t)B * K * 4);
    unsigned long long* maskT = (unsigned long long*) alloc((size_t)B * K * NCHUNK * 8);
    unsigned long long* nzT   = (unsigned long long*) alloc((size_t)B * NCHUNK * NCHUNK * 8);
    (void)ws_size; // needs ~6.5 MB

    nms_score_kernel<<<dim3((N + STILE - 1) / STILE, B), 256, 0, stream>>>(x, scores, cls_id);
    nms_select_kernel<<<B, 1024, 0, stream>>>(scores, x, cls_id,
                                              top_s, boxes, clsk, shifted, area);
    nms_mask_kernel<<<dim3(NCHUNK * (NCHUNK + 1) / 2, B), 64, 0, stream>>>(shifted, area, maskT, nzT);
    nms_reduce_out_kernel<<<B, 1024, 0, stream>>>(maskT, nzT, top_s, boxes, clsk, out);
}